// Round 15
// baseline (243.981 us; speedup 1.0000x reference)
//
#include <hip/hip_runtime.h>
#include <hip/hip_bf16.h>
#include <cstdint>
#include <cstddef>

// Problem constants: B=2, T=2048, E=1024, H=16, D=64, BH=32
#define SCALING_F 0.08838834764831845f
#define FIXED_MAX 8.0f

typedef short bf16x8 __attribute__((ext_vector_type(8)));
typedef float f32x4 __attribute__((ext_vector_type(4)));

__device__ __forceinline__ unsigned short f2bf(float f) {
  unsigned int u = __float_as_uint(f);
  u += 0x7fffu + ((u >> 16) & 1u);   // round-to-nearest-even
  return (unsigned short)(u >> 16);
}

__device__ __forceinline__ f32x4 mfma16(bf16x8 a, bf16x8 b, f32x4 c) {
  return __builtin_amdgcn_mfma_f32_16x16x32_bf16(a, b, c, 0, 0, 0);
}

typedef const __attribute__((address_space(1))) void* as1cp;
typedef __attribute__((address_space(3))) void* as3p;
__device__ __forceinline__ void gload16(const void* g, void* s) {
  __builtin_amdgcn_global_load_lds((as1cp)g, (as3p)s, 16, 0, 0);
}
// Streaming cache policy for the zero-reuse bias: NT(2) demotes in near caches,
// +SC1(16) widens scope so the line avoids allocating in L2/L3 entirely
// (mask[16x reuse] stays L3-resident, K/V[4x reuse] stay L2-resident).
__device__ __forceinline__ void gload16nt(const void* g, void* s) {
  __builtin_amdgcn_global_load_lds((as1cp)g, (as3p)s, 16, 0, 18);
}
#define SB __builtin_amdgcn_sched_barrier(0)

// ---------------- fused fp32 -> bf16 cast (X + Wq + Wk + Wv + Wo, one launch) ----------------
__global__ void cast_all_kernel(const float* __restrict__ hs,
                                const float* __restrict__ Wq,
                                const float* __restrict__ Wk,
                                const float* __restrict__ Wv,
                                const float* __restrict__ Wo,
                                unsigned short* __restrict__ dst) {
  int i = (blockIdx.x * blockDim.x + threadIdx.x) * 4;  // dst elem index, 8388608 total
  const float* src;
  int off;
  if (i < 4194304) {
    src = hs; off = i;
  } else {
    int j = i - 4194304;
    int which = j >> 20;
    off = j & 1048575;
    src = (which == 0) ? Wq : (which == 1) ? Wk : (which == 2) ? Wv : Wo;
  }
  // single-use fp32 source -> non-temporal load (clang ext-vector type required)
  f32x4 v = __builtin_nontemporal_load(reinterpret_cast<const f32x4*>(src + off));
  ushort4 o;
  o.x = f2bf(v.x); o.y = f2bf(v.y); o.z = f2bf(v.z); o.w = f2bf(v.w);
  *reinterpret_cast<ushort4*>(dst + i) = o;
}

// ---------------- fused QKV GEMM: C = X(4096x1024) * W^T + bias ----------------
__global__ __launch_bounds__(256) void gemm_qkv(
    const unsigned short* __restrict__ Xb,
    const unsigned short* __restrict__ Wb,
    const float* __restrict__ bq, const float* __restrict__ bk,
    const float* __restrict__ bv,
    unsigned short* __restrict__ Qb, unsigned short* __restrict__ Kb,
    unsigned short* __restrict__ Vt) {
  __shared__ unsigned short As[128 * 32];
  __shared__ unsigned short Bs[128 * 32];
  const int tid = threadIdx.x, lane = tid & 63, wid = tid >> 6;
  const int mat = blockIdx.y >> 3;
  const int m0 = blockIdx.x * 128, n0 = (blockIdx.y & 7) * 128;
  const unsigned short* W = Wb + (size_t)mat * 1048576;
  const float* bias = (mat == 0) ? bq : (mat == 1 ? bk : bv);

  f32x4 z = {0.f, 0.f, 0.f, 0.f};
  f32x4 acc[4][4];
#pragma unroll
  for (int i = 0; i < 4; ++i)
#pragma unroll
    for (int j = 0; j < 4; ++j) acc[i][j] = z;

  const int wm = wid >> 1, wn = wid & 1;
  const int lr = lane & 15, lg = lane >> 4;

  for (int kt = 0; kt < 1024; kt += 32) {
    __syncthreads();
#pragma unroll
    for (int c = 0; c < 2; ++c) {
      int le = (wid * 2 + c) * 512 + lane * 8;
      int row = le >> 5, col = le & 31;
      gload16(Xb + (size_t)(m0 + row) * 1024 + kt + col,
              (void*)(As + (wid * 2 + c) * 512));
      gload16(W + (size_t)(n0 + row) * 1024 + kt + col,
              (void*)(Bs + (wid * 2 + c) * 512));
    }
    __syncthreads();
    bf16x8 a[4], b[4];
#pragma unroll
    for (int f = 0; f < 4; ++f) {
      a[f] = *reinterpret_cast<const bf16x8*>(As + (wm * 64 + f * 16 + lr) * 32 + lg * 8);
      b[f] = *reinterpret_cast<const bf16x8*>(Bs + (wn * 64 + f * 16 + lr) * 32 + lg * 8);
    }
#pragma unroll
    for (int i = 0; i < 4; ++i)
#pragma unroll
      for (int j = 0; j < 4; ++j) acc[i][j] = mfma16(a[i], b[j], acc[i][j]);
  }

  if (mat == 2) {
#pragma unroll
    for (int i = 0; i < 4; ++i) {
      int t0g = m0 + wm * 64 + i * 16 + lg * 4;
      int bb_ = t0g >> 11, tt_ = t0g & 2047;
#pragma unroll
      for (int j = 0; j < 4; ++j) {
        int gn = n0 + wn * 64 + j * 16 + lr;
        int h2 = gn >> 6, d2 = gn & 63;
        float bs = bias[gn];
        ushort4 pk;
        pk.x = f2bf(acc[i][j][0] + bs);
        pk.y = f2bf(acc[i][j][1] + bs);
        pk.z = f2bf(acc[i][j][2] + bs);
        pk.w = f2bf(acc[i][j][3] + bs);
        *reinterpret_cast<ushort4*>(
            Vt + (((size_t)(bb_ * 16 + h2)) * 64 + d2) * 2048 + tt_) = pk;
      }
    }
  } else {
    const float scale = (mat == 0) ? SCALING_F : 1.0f;
    unsigned short* P = (mat == 0) ? Qb : Kb;
#pragma unroll
    for (int i = 0; i < 4; ++i) {
#pragma unroll
      for (int j = 0; j < 4; ++j) {
#pragma unroll
        for (int r = 0; r < 4; ++r) {
          int gm = m0 + wm * 64 + i * 16 + lg * 4 + r;
          int gn = n0 + wn * 64 + j * 16 + lr;
          float val = (acc[i][j][r] + bias[gn]) * scale;
          int b_ = gm >> 11, t_ = gm & 2047;
          int h_ = gn >> 6, d_ = gn & 63;
          P[(((size_t)(b_ * 16 + h_)) * 2048 + t_) * 64 + d_] = f2bf(val);
        }
      }
    }
  }
}

// ---------------- output GEMM: out = AO(4096x1024) * Wo^T + bo (fp32) ----------------
__global__ __launch_bounds__(256) void gemm_out(
    const unsigned short* __restrict__ Ab, const unsigned short* __restrict__ Wo,
    const float* __restrict__ bo, float* __restrict__ C) {
  __shared__ unsigned short As[128 * 32];
  __shared__ unsigned short Bs[128 * 32];
  const int tid = threadIdx.x, lane = tid & 63, wid = tid >> 6;
  const int m0 = blockIdx.x * 128, n0 = blockIdx.y * 128;

  f32x4 z = {0.f, 0.f, 0.f, 0.f};
  f32x4 acc[4][4];
#pragma unroll
  for (int i = 0; i < 4; ++i)
#pragma unroll
    for (int j = 0; j < 4; ++j) acc[i][j] = z;

  const int wm = wid >> 1, wn = wid & 1;
  const int lr = lane & 15, lg = lane >> 4;

  for (int kt = 0; kt < 1024; kt += 32) {
    __syncthreads();
#pragma unroll
    for (int c = 0; c < 2; ++c) {
      int le = (wid * 2 + c) * 512 + lane * 8;
      int row = le >> 5, col = le & 31;
      gload16(Ab + (size_t)(m0 + row) * 1024 + kt + col,
              (void*)(As + (wid * 2 + c) * 512));
      gload16(Wo + (size_t)(n0 + row) * 1024 + kt + col,
              (void*)(Bs + (wid * 2 + c) * 512));
    }
    __syncthreads();
    bf16x8 a[4], b[4];
#pragma unroll
    for (int f = 0; f < 4; ++f) {
      a[f] = *reinterpret_cast<const bf16x8*>(As + (wm * 64 + f * 16 + lr) * 32 + lg * 8);
      b[f] = *reinterpret_cast<const bf16x8*>(Bs + (wn * 64 + f * 16 + lr) * 32 + lg * 8);
    }
#pragma unroll
    for (int i = 0; i < 4; ++i)
#pragma unroll
      for (int j = 0; j < 4; ++j) acc[i][j] = mfma16(a[i], b[j], acc[i][j]);
  }

#pragma unroll
  for (int i = 0; i < 4; ++i)
#pragma unroll
    for (int j = 0; j < 4; ++j)
#pragma unroll
      for (int r = 0; r < 4; ++r) {
        int gm = m0 + wm * 64 + i * 16 + lg * 4 + r;
        int gn = n0 + wn * 64 + j * 16 + lr;
        // final output, never re-read on device -> non-temporal store
        __builtin_nontemporal_store(acc[i][j][r] + bo[gn],
                                    C + (size_t)gm * 1024 + gn);
      }
}

// ---------------- flash attention (r5/r12 structure + streaming-policy bias) ----------------
// grid 1024 (XCD-swizzled), 4 waves; wave owns 16 q-rows; kv tiles of 64.
// K/V/bias staged to LDS via global_load_lds (pre-swizzled source, swizzled read);
// bias double-buffered with NT|SC1 streaming policy (zero reuse -> no L2/L3 alloc);
// mask distance-1 register ping-pong; end-of-tile vmcnt(4) leaves mask in flight.
// Fixed-max softmax. LDS 72 KB -> 2 blocks/CU.
__global__ __launch_bounds__(256, 2) void attn_kernel(
    const unsigned short* __restrict__ Qb,  // (bh, t, d) bf16, pre-scaled
    const unsigned short* __restrict__ Kb,  // (bh, t, d) bf16
    const unsigned short* __restrict__ Vt,  // (bh, d, t) bf16
    const float* __restrict__ bias,         // (32, 2048, 2048) fp32
    const float* __restrict__ mask,         // (2, 1, 2048, 2048) fp32
    const float* __restrict__ c_attn,       // (16) fp32
    unsigned short* __restrict__ AO) {      // (4096, 1024) bf16
  __shared__ unsigned short Ks[2][4096];    // 16 KB: 64 kv x 64 d, swizzled slots
  __shared__ unsigned short Vs[2][4096];    // 16 KB: 64 d x 64 t, swizzled slots
  __shared__ unsigned short Ps[4][1024];    // 8 KB: per-wave 16x64, XOR-swizzled
  __shared__ float Bs[2][4][1024];          // 32 KB: per-wave 16q x 64s bias

  const int tid = threadIdx.x, lane = tid & 63, wid = tid >> 6;
  const int bid = blockIdx.x;
  const int swz = (bid & 7) * 128 + (bid >> 3);
  const int bh = swz >> 5;
  const int b_ = bh >> 4, h_ = bh & 15;
  const int q0 = (swz & 31) * 64 + wid * 16;
  const int lr = lane & 15, lg = lane >> 4;

  // Q fragments (B-operand: col q=lr, k=d)
  const unsigned short* Qp = Qb + ((size_t)bh * 2048 + q0) * 64;
  bf16x8 bq0 = *reinterpret_cast<const bf16x8*>(Qp + lr * 64 + lg * 8);
  bf16x8 bq1 = *reinterpret_cast<const bf16x8*>(Qp + lr * 64 + 32 + lg * 8);

  // K/V staging geometry (16B slot s -> row s>>3, col16 (s&7)^(row&7))
  const unsigned short* Kbase = Kb + (size_t)bh * 131072;  // (t, d)
  const unsigned short* Vbase = Vt + (size_t)bh * 131072;  // (d, t)
  const int s0 = tid, s1 = 256 + tid;
  const int r0 = s0 >> 3, c0 = (s0 & 7) ^ (r0 & 7);
  const int r1 = s1 >> 3, c1 = (s1 & 7) ^ (r1 & 7);
  const int koff0 = r0 * 64 + c0 * 8,   koff1 = r1 * 64 + c1 * 8;
  const int voff0 = r0 * 2048 + c0 * 8, voff1 = r1 * 2048 + c1 * 8;
  const int dstbase = wid * 512;

  // bias staging geometry: instr j covers rows 4j+ro, lane slot sl, source slot
  // sl ^ ((4j+ro)&7); only two xor values: sl^ro and sl^ro^4.
  const int ro = lane >> 4, sl = lane & 15;
  const float* bias_bh = bias + (size_t)bh * 4194304;
  const float* bsrc0 = bias_bh + (size_t)(q0 + ro) * 2048 + ((sl ^ ro) << 2);
  const float* bsrc1 = bias_bh + (size_t)(q0 + 4 + ro) * 2048 + (((sl ^ ro) ^ 4) << 2);

  auto stage = [&](int t) {  // stage K/V + bias for kv-tile t into buffers t&1
    const int kv0 = t << 6;
    const unsigned short* Kp = Kbase + kv0 * 64;
    const unsigned short* Vp = Vbase + kv0;
    unsigned short* kd = &Ks[t & 1][dstbase];
    unsigned short* vd = &Vs[t & 1][dstbase];
    gload16(Kp + koff0, kd);
    gload16(Kp + koff1, kd + 2048);
    gload16(Vp + voff0, vd);
    gload16(Vp + voff1, vd + 2048);
    float* bd = &Bs[t & 1][wid][0];
    gload16nt(bsrc0 + kv0, bd);
    gload16nt(bsrc1 + kv0, (void*)((char*)bd + 1024));
    gload16nt(bsrc0 + 16384 + kv0, (void*)((char*)bd + 2048));
    gload16nt(bsrc1 + 16384 + kv0, (void*)((char*)bd + 3072));
  };

  f32x4 z = {0.f, 0.f, 0.f, 0.f};
  f32x4 o[4] = {z, z, z, z};
  float l_q = 0.f;

  const float* mptr = mask + (size_t)b_ * 4194304 + (size_t)(q0 + lr) * 2048 + lg * 4;
  char* pbase = (char*)(&Ps[wid][0]);
  const int pb0 = (lr * 128 + lg * 16) ^ ((lr & 7) << 4);
  const int pb1 = (lr * 128 + 64 + lg * 16) ^ ((lr & 7) << 4);
  const int fe0 = lr * 64 + ((lg ^ (lr & 7)) * 8);
  const int fe1 = lr * 64 + (((4 + lg) ^ (lr & 7)) * 8);

  auto loadMask = [&](float4* mm, int t) {
    const int kv0 = (t & 31) << 6;
#pragma unroll
    for (int f = 0; f < 4; ++f)
      mm[f] = *reinterpret_cast<const float4*>(mptr + kv0 + f * 16);
  };

  auto tile = [&](int i, float4* mmCur, float4* mmNext) {
    stage((i + 1) & 31);
    SB;
    loadMask(mmNext, i + 1);

    // QK^T from Ks
    const unsigned short* Kt = &Ks[i & 1][0];
    f32x4 sacc[4] = {z, z, z, z};
    __builtin_amdgcn_s_setprio(1);
#pragma unroll
    for (int f = 0; f < 4; ++f) {
      bf16x8 k0 = *reinterpret_cast<const bf16x8*>(Kt + f * 1024 + fe0);
      bf16x8 k1 = *reinterpret_cast<const bf16x8*>(Kt + f * 1024 + fe1);
      sacc[f] = mfma16(k0, bq0, sacc[f]);
      sacc[f] = mfma16(k1, bq1, sacc[f]);
    }
    __builtin_amdgcn_s_setprio(0);

    // bias from LDS (conflict-free swizzled f32x4 reads)
    const char* bwave = (const char*)&Bs[i & 1][wid][0];
    float4 bv[4];
#pragma unroll
    for (int f = 0; f < 4; ++f)
      bv[f] = *reinterpret_cast<const float4*>(
          bwave + lr * 256 + (((f * 4 + lg) ^ (lr & 7)) << 4));

    // P = exp(S + bias + mask - FIXED_MAX); accumulate per-lane partial l
#pragma unroll
    for (int f = 0; f < 4; ++f) {
      float p0 = __expf(sacc[f][0] + bv[f].x + mmCur[f].x - FIXED_MAX);
      float p1 = __expf(sacc[f][1] + bv[f].y + mmCur[f].y - FIXED_MAX);
      float p2 = __expf(sacc[f][2] + bv[f].z + mmCur[f].z - FIXED_MAX);
      float p3 = __expf(sacc[f][3] + bv[f].w + mmCur[f].w - FIXED_MAX);
      l_q += (p0 + p1) + (p2 + p3);
      uint2 w;
      w.x = (unsigned)f2bf(p0) | ((unsigned)f2bf(p1) << 16);
      w.y = (unsigned)f2bf(p2) | ((unsigned)f2bf(p3) << 16);
      int byte = (lr * 128 + (f * 16 + lg * 4) * 2) ^ ((lr & 7) << 4);
      *reinterpret_cast<uint2*>(pbase + byte) = w;
    }
    asm volatile("s_waitcnt lgkmcnt(0)" ::: "memory");
    SB;
    bf16x8 pa0 = *reinterpret_cast<const bf16x8*>(pbase + pb0);
    bf16x8 pa1 = *reinterpret_cast<const bf16x8*>(pbase + pb1);

    // PV from Vs
    const unsigned short* Vtile = &Vs[i & 1][0];
    __builtin_amdgcn_s_setprio(1);
#pragma unroll
    for (int fd = 0; fd < 4; ++fd) {
      bf16x8 v0 = *reinterpret_cast<const bf16x8*>(Vtile + fd * 1024 + fe0);
      bf16x8 v1 = *reinterpret_cast<const bf16x8*>(Vtile + fd * 1024 + fe1);
      o[fd] = mfma16(pa0, v0, o[fd]);
      o[fd] = mfma16(pa1, v1, o[fd]);
    }
    __builtin_amdgcn_s_setprio(0);

    // drain K/V+bias stage (8 oldest); leave the 4 mask loads in flight
    SB;
    asm volatile("s_waitcnt vmcnt(4)" ::: "memory");
    __builtin_amdgcn_s_barrier();
    SB;
  };

  float4 mmA[4], mmB[4];
  // prologue: stage tile 0, mask 0
  stage(0);
  SB;
  loadMask(mmA, 0);
  asm volatile("s_waitcnt vmcnt(4)" ::: "memory");
  __builtin_amdgcn_s_barrier();
  SB;

  for (int i = 0; i < 32; i += 2) {
    tile(i, mmA, mmB);
    tile(i + 1, mmB, mmA);
  }

  // reduce l over the 4 lane-groups, normalize, scale, write
  l_q += __shfl_xor(l_q, 16);
  l_q += __shfl_xor(l_q, 32);
  float linv = 1.0f / l_q;
  float li0 = __shfl(linv, lg * 4 + 0);
  float li1 = __shfl(linv, lg * 4 + 1);
  float li2 = __shfl(linv, lg * 4 + 2);
  float li3 = __shfl(linv, lg * 4 + 3);
  const float ca = c_attn[h_];
  float li[4] = {li0, li1, li2, li3};
#pragma unroll
  for (int fd = 0; fd < 4; ++fd) {
#pragma unroll
    for (int r = 0; r < 4; ++r) {
      int q_ = q0 + lg * 4 + r;
      int d_ = fd * 16 + lr;
      AO[((size_t)(b_ * 2048 + q_)) * 1024 + h_ * 64 + d_] = f2bf(o[fd][r] * li[r] * ca);
    }
  }
}

extern "C" void kernel_launch(void* const* d_in, const int* in_sizes, int n_in,
                              void* d_out, int out_size, void* d_ws, size_t ws_size,
                              hipStream_t stream) {
  const float* hs   = (const float*)d_in[0];
  const float* bias = (const float*)d_in[1];
  const float* mask = (const float*)d_in[2];
  const float* Wq   = (const float*)d_in[3];
  const float* bq   = (const float*)d_in[4];
  const float* Wk   = (const float*)d_in[5];
  const float* bk   = (const float*)d_in[6];
  const float* Wv   = (const float*)d_in[7];
  const float* bv   = (const float*)d_in[8];
  const float* Wo   = (const float*)d_in[9];
  const float* bo   = (const float*)d_in[10];
  const float* ca   = (const float*)d_in[11];
  float* out = (float*)d_out;

  unsigned short* ws = (unsigned short*)d_ws;
  unsigned short* Xb  = ws;                  // [0, 4194304)
  unsigned short* Wqb = ws + 4194304;        // Wq,Wk,Wv at 1048576 strides
  unsigned short* Wob = Wqb + 3 * 1048576;   // [7340032, 8388608)
  unsigned short* Qb  = ws + 8388608;
  unsigned short* Kb  = Qb + 4194304;
  unsigned short* Vt  = Kb + 4194304;
  unsigned short* AO  = Vt + 4194304;

  cast_all_kernel<<<8192, 256, 0, stream>>>(hs, Wq, Wk, Wv, Wo, ws);

  gemm_qkv<<<dim3(32, 24), 256, 0, stream>>>(Xb, Wqb, bq, bk, bv, Qb, Kb, Vt);
  attn_kernel<<<1024, 256, 0, stream>>>(Qb, Kb, Vt, bias, mask, ca, AO);
  gemm_out<<<dim3(32, 8), 256, 0, stream>>>(AO, Wob, bo, out);
}

// Round 16
// 241.686 us; speedup vs baseline: 1.0095x; 1.0095x over previous
//
#include <hip/hip_runtime.h>
#include <hip/hip_bf16.h>
#include <cstdint>
#include <cstddef>

// Problem constants: B=2, T=2048, E=1024, H=16, D=64, BH=32
#define SCALING_F 0.08838834764831845f
#define FIXED_MAX 8.0f

typedef short bf16x8 __attribute__((ext_vector_type(8)));
typedef float f32x4 __attribute__((ext_vector_type(4)));

__device__ __forceinline__ unsigned short f2bf(float f) {
  unsigned int u = __float_as_uint(f);
  u += 0x7fffu + ((u >> 16) & 1u);   // round-to-nearest-even
  return (unsigned short)(u >> 16);
}

__device__ __forceinline__ f32x4 mfma16(bf16x8 a, bf16x8 b, f32x4 c) {
  return __builtin_amdgcn_mfma_f32_16x16x32_bf16(a, b, c, 0, 0, 0);
}

typedef const __attribute__((address_space(1))) void* as1cp;
typedef __attribute__((address_space(3))) void* as3p;
__device__ __forceinline__ void gload16(const void* g, void* s) {
  __builtin_amdgcn_global_load_lds((as1cp)g, (as3p)s, 16, 0, 0);
}
// NT (non-temporal) cache policy for the zero-reuse bias stream (gfx940+ CPol NT=2):
// bias is read exactly once -> don't let it flush L2/L3 (mask/K/V reuse lives there).
// Verified r13: -12.4 us vs normal policy. (NT|SC1=18 tested r15: no further gain.)
__device__ __forceinline__ void gload16nt(const void* g, void* s) {
  __builtin_amdgcn_global_load_lds((as1cp)g, (as3p)s, 16, 0, 2);
}
#define SB __builtin_amdgcn_sched_barrier(0)

// ---------------- fused fp32 -> bf16 cast (X + Wq + Wk + Wv + Wo, one launch) ----------------
__global__ void cast_all_kernel(const float* __restrict__ hs,
                                const float* __restrict__ Wq,
                                const float* __restrict__ Wk,
                                const float* __restrict__ Wv,
                                const float* __restrict__ Wo,
                                unsigned short* __restrict__ dst) {
  int i = (blockIdx.x * blockDim.x + threadIdx.x) * 4;  // dst elem index, 8388608 total
  const float* src;
  int off;
  if (i < 4194304) {
    src = hs; off = i;
  } else {
    int j = i - 4194304;
    int which = j >> 20;
    off = j & 1048575;
    src = (which == 0) ? Wq : (which == 1) ? Wk : (which == 2) ? Wv : Wo;
  }
  float4 v = *reinterpret_cast<const float4*>(src + off);
  ushort4 o;
  o.x = f2bf(v.x); o.y = f2bf(v.y); o.z = f2bf(v.z); o.w = f2bf(v.w);
  *reinterpret_cast<ushort4*>(dst + i) = o;
}

// ---------------- fused QKV GEMM: C = X(4096x1024) * W^T + bias ----------------
__global__ __launch_bounds__(256) void gemm_qkv(
    const unsigned short* __restrict__ Xb,
    const unsigned short* __restrict__ Wb,
    const float* __restrict__ bq, const float* __restrict__ bk,
    const float* __restrict__ bv,
    unsigned short* __restrict__ Qb, unsigned short* __restrict__ Kb,
    unsigned short* __restrict__ Vt) {
  __shared__ unsigned short As[128 * 32];
  __shared__ unsigned short Bs[128 * 32];
  const int tid = threadIdx.x, lane = tid & 63, wid = tid >> 6;
  const int mat = blockIdx.y >> 3;
  const int m0 = blockIdx.x * 128, n0 = (blockIdx.y & 7) * 128;
  const unsigned short* W = Wb + (size_t)mat * 1048576;
  const float* bias = (mat == 0) ? bq : (mat == 1 ? bk : bv);

  f32x4 z = {0.f, 0.f, 0.f, 0.f};
  f32x4 acc[4][4];
#pragma unroll
  for (int i = 0; i < 4; ++i)
#pragma unroll
    for (int j = 0; j < 4; ++j) acc[i][j] = z;

  const int wm = wid >> 1, wn = wid & 1;
  const int lr = lane & 15, lg = lane >> 4;

  for (int kt = 0; kt < 1024; kt += 32) {
    __syncthreads();
#pragma unroll
    for (int c = 0; c < 2; ++c) {
      int le = (wid * 2 + c) * 512 + lane * 8;
      int row = le >> 5, col = le & 31;
      gload16(Xb + (size_t)(m0 + row) * 1024 + kt + col,
              (void*)(As + (wid * 2 + c) * 512));
      gload16(W + (size_t)(n0 + row) * 1024 + kt + col,
              (void*)(Bs + (wid * 2 + c) * 512));
    }
    __syncthreads();
    bf16x8 a[4], b[4];
#pragma unroll
    for (int f = 0; f < 4; ++f) {
      a[f] = *reinterpret_cast<const bf16x8*>(As + (wm * 64 + f * 16 + lr) * 32 + lg * 8);
      b[f] = *reinterpret_cast<const bf16x8*>(Bs + (wn * 64 + f * 16 + lr) * 32 + lg * 8);
    }
#pragma unroll
    for (int i = 0; i < 4; ++i)
#pragma unroll
      for (int j = 0; j < 4; ++j) acc[i][j] = mfma16(a[i], b[j], acc[i][j]);
  }

  if (mat == 2) {
#pragma unroll
    for (int i = 0; i < 4; ++i) {
      int t0g = m0 + wm * 64 + i * 16 + lg * 4;
      int bb_ = t0g >> 11, tt_ = t0g & 2047;
#pragma unroll
      for (int j = 0; j < 4; ++j) {
        int gn = n0 + wn * 64 + j * 16 + lr;
        int h2 = gn >> 6, d2 = gn & 63;
        float bs = bias[gn];
        ushort4 pk;
        pk.x = f2bf(acc[i][j][0] + bs);
        pk.y = f2bf(acc[i][j][1] + bs);
        pk.z = f2bf(acc[i][j][2] + bs);
        pk.w = f2bf(acc[i][j][3] + bs);
        *reinterpret_cast<ushort4*>(
            Vt + (((size_t)(bb_ * 16 + h2)) * 64 + d2) * 2048 + tt_) = pk;
      }
    }
  } else {
    const float scale = (mat == 0) ? SCALING_F : 1.0f;
    unsigned short* P = (mat == 0) ? Qb : Kb;
#pragma unroll
    for (int i = 0; i < 4; ++i) {
#pragma unroll
      for (int j = 0; j < 4; ++j) {
#pragma unroll
        for (int r = 0; r < 4; ++r) {
          int gm = m0 + wm * 64 + i * 16 + lg * 4 + r;
          int gn = n0 + wn * 64 + j * 16 + lr;
          float val = (acc[i][j][r] + bias[gn]) * scale;
          int b_ = gm >> 11, t_ = gm & 2047;
          int h_ = gn >> 6, d_ = gn & 63;
          P[(((size_t)(b_ * 16 + h_)) * 2048 + t_) * 64 + d_] = f2bf(val);
        }
      }
    }
  }
}

// ---------------- output GEMM: out = AO(4096x1024) * Wo^T + bo (fp32) ----------------
__global__ __launch_bounds__(256) void gemm_out(
    const unsigned short* __restrict__ Ab, const unsigned short* __restrict__ Wo,
    const float* __restrict__ bo, float* __restrict__ C) {
  __shared__ unsigned short As[128 * 32];
  __shared__ unsigned short Bs[128 * 32];
  const int tid = threadIdx.x, lane = tid & 63, wid = tid >> 6;
  const int m0 = blockIdx.x * 128, n0 = blockIdx.y * 128;

  f32x4 z = {0.f, 0.f, 0.f, 0.f};
  f32x4 acc[4][4];
#pragma unroll
  for (int i = 0; i < 4; ++i)
#pragma unroll
    for (int j = 0; j < 4; ++j) acc[i][j] = z;

  const int wm = wid >> 1, wn = wid & 1;
  const int lr = lane & 15, lg = lane >> 4;

  for (int kt = 0; kt < 1024; kt += 32) {
    __syncthreads();
#pragma unroll
    for (int c = 0; c < 2; ++c) {
      int le = (wid * 2 + c) * 512 + lane * 8;
      int row = le >> 5, col = le & 31;
      gload16(Ab + (size_t)(m0 + row) * 1024 + kt + col,
              (void*)(As + (wid * 2 + c) * 512));
      gload16(Wo + (size_t)(n0 + row) * 1024 + kt + col,
              (void*)(Bs + (wid * 2 + c) * 512));
    }
    __syncthreads();
    bf16x8 a[4], b[4];
#pragma unroll
    for (int f = 0; f < 4; ++f) {
      a[f] = *reinterpret_cast<const bf16x8*>(As + (wm * 64 + f * 16 + lr) * 32 + lg * 8);
      b[f] = *reinterpret_cast<const bf16x8*>(Bs + (wn * 64 + f * 16 + lr) * 32 + lg * 8);
    }
#pragma unroll
    for (int i = 0; i < 4; ++i)
#pragma unroll
      for (int j = 0; j < 4; ++j) acc[i][j] = mfma16(a[i], b[j], acc[i][j]);
  }

#pragma unroll
  for (int i = 0; i < 4; ++i)
#pragma unroll
    for (int j = 0; j < 4; ++j)
#pragma unroll
      for (int r = 0; r < 4; ++r) {
        int gm = m0 + wm * 64 + i * 16 + lg * 4 + r;
        int gn = n0 + wn * 64 + j * 16 + lr;
        C[(size_t)gm * 1024 + gn] = acc[i][j][r] + bo[gn];
      }
}

// ---------------- flash attention (r5 structure + NT bias stream; verified best) ----------------
// grid 1024 (XCD-swizzled), 4 waves; wave owns 16 q-rows; kv tiles of 64.
// K/V/bias staged to LDS via global_load_lds (pre-swizzled source, swizzled read);
// bias double-buffered with NT cache policy (zero reuse -> no L2/L3 thrash of
// mask[16x reuse, L3] and K/V[4x reuse, L2]); mask distance-1 register ping-pong;
// end-of-tile vmcnt(4) leaves mask in flight. Fixed-max softmax. 72 KB LDS -> 2 blocks/CU.
__global__ __launch_bounds__(256, 2) void attn_kernel(
    const unsigned short* __restrict__ Qb,  // (bh, t, d) bf16, pre-scaled
    const unsigned short* __restrict__ Kb,  // (bh, t, d) bf16
    const unsigned short* __restrict__ Vt,  // (bh, d, t) bf16
    const float* __restrict__ bias,         // (32, 2048, 2048) fp32
    const float* __restrict__ mask,         // (2, 1, 2048, 2048) fp32
    const float* __restrict__ c_attn,       // (16) fp32
    unsigned short* __restrict__ AO) {      // (4096, 1024) bf16
  __shared__ unsigned short Ks[2][4096];    // 16 KB: 64 kv x 64 d, swizzled slots
  __shared__ unsigned short Vs[2][4096];    // 16 KB: 64 d x 64 t, swizzled slots
  __shared__ unsigned short Ps[4][1024];    // 8 KB: per-wave 16x64, XOR-swizzled
  __shared__ float Bs[2][4][1024];          // 32 KB: per-wave 16q x 64s bias

  const int tid = threadIdx.x, lane = tid & 63, wid = tid >> 6;
  const int bid = blockIdx.x;
  const int swz = (bid & 7) * 128 + (bid >> 3);
  const int bh = swz >> 5;
  const int b_ = bh >> 4, h_ = bh & 15;
  const int q0 = (swz & 31) * 64 + wid * 16;
  const int lr = lane & 15, lg = lane >> 4;

  // Q fragments (B-operand: col q=lr, k=d)
  const unsigned short* Qp = Qb + ((size_t)bh * 2048 + q0) * 64;
  bf16x8 bq0 = *reinterpret_cast<const bf16x8*>(Qp + lr * 64 + lg * 8);
  bf16x8 bq1 = *reinterpret_cast<const bf16x8*>(Qp + lr * 64 + 32 + lg * 8);

  // K/V staging geometry (16B slot s -> row s>>3, col16 (s&7)^(row&7))
  const unsigned short* Kbase = Kb + (size_t)bh * 131072;  // (t, d)
  const unsigned short* Vbase = Vt + (size_t)bh * 131072;  // (d, t)
  const int s0 = tid, s1 = 256 + tid;
  const int r0 = s0 >> 3, c0 = (s0 & 7) ^ (r0 & 7);
  const int r1 = s1 >> 3, c1 = (s1 & 7) ^ (r1 & 7);
  const int koff0 = r0 * 64 + c0 * 8,   koff1 = r1 * 64 + c1 * 8;
  const int voff0 = r0 * 2048 + c0 * 8, voff1 = r1 * 2048 + c1 * 8;
  const int dstbase = wid * 512;

  // bias staging geometry: instr j covers rows 4j+ro, lane slot sl, source slot
  // sl ^ ((4j+ro)&7); only two xor values: sl^ro and sl^ro^4.
  const int ro = lane >> 4, sl = lane & 15;
  const float* bias_bh = bias + (size_t)bh * 4194304;
  const float* bsrc0 = bias_bh + (size_t)(q0 + ro) * 2048 + ((sl ^ ro) << 2);
  const float* bsrc1 = bias_bh + (size_t)(q0 + 4 + ro) * 2048 + (((sl ^ ro) ^ 4) << 2);

  auto stage = [&](int t) {  // stage K/V + bias for kv-tile t into buffers t&1
    const int kv0 = t << 6;
    const unsigned short* Kp = Kbase + kv0 * 64;
    const unsigned short* Vp = Vbase + kv0;
    unsigned short* kd = &Ks[t & 1][dstbase];
    unsigned short* vd = &Vs[t & 1][dstbase];
    gload16(Kp + koff0, kd);
    gload16(Kp + koff1, kd + 2048);
    gload16(Vp + voff0, vd);
    gload16(Vp + voff1, vd + 2048);
    float* bd = &Bs[t & 1][wid][0];
    gload16nt(bsrc0 + kv0, bd);
    gload16nt(bsrc1 + kv0, (void*)((char*)bd + 1024));
    gload16nt(bsrc0 + 16384 + kv0, (void*)((char*)bd + 2048));
    gload16nt(bsrc1 + 16384 + kv0, (void*)((char*)bd + 3072));
  };

  f32x4 z = {0.f, 0.f, 0.f, 0.f};
  f32x4 o[4] = {z, z, z, z};
  float l_q = 0.f;

  const float* mptr = mask + (size_t)b_ * 4194304 + (size_t)(q0 + lr) * 2048 + lg * 4;
  char* pbase = (char*)(&Ps[wid][0]);
  const int pb0 = (lr * 128 + lg * 16) ^ ((lr & 7) << 4);
  const int pb1 = (lr * 128 + 64 + lg * 16) ^ ((lr & 7) << 4);
  const int fe0 = lr * 64 + ((lg ^ (lr & 7)) * 8);
  const int fe1 = lr * 64 + (((4 + lg) ^ (lr & 7)) * 8);

  auto loadMask = [&](float4* mm, int t) {
    const int kv0 = (t & 31) << 6;
#pragma unroll
    for (int f = 0; f < 4; ++f)
      mm[f] = *reinterpret_cast<const float4*>(mptr + kv0 + f * 16);
  };

  auto tile = [&](int i, float4* mmCur, float4* mmNext) {
    stage((i + 1) & 31);
    SB;
    loadMask(mmNext, i + 1);

    // QK^T from Ks
    const unsigned short* Kt = &Ks[i & 1][0];
    f32x4 sacc[4] = {z, z, z, z};
    __builtin_amdgcn_s_setprio(1);
#pragma unroll
    for (int f = 0; f < 4; ++f) {
      bf16x8 k0 = *reinterpret_cast<const bf16x8*>(Kt + f * 1024 + fe0);
      bf16x8 k1 = *reinterpret_cast<const bf16x8*>(Kt + f * 1024 + fe1);
      sacc[f] = mfma16(k0, bq0, sacc[f]);
      sacc[f] = mfma16(k1, bq1, sacc[f]);
    }
    __builtin_amdgcn_s_setprio(0);

    // bias from LDS (conflict-free swizzled f32x4 reads)
    const char* bwave = (const char*)&Bs[i & 1][wid][0];
    float4 bv[4];
#pragma unroll
    for (int f = 0; f < 4; ++f)
      bv[f] = *reinterpret_cast<const float4*>(
          bwave + lr * 256 + (((f * 4 + lg) ^ (lr & 7)) << 4));

    // P = exp(S + bias + mask - FIXED_MAX); accumulate per-lane partial l
#pragma unroll
    for (int f = 0; f < 4; ++f) {
      float p0 = __expf(sacc[f][0] + bv[f].x + mmCur[f].x - FIXED_MAX);
      float p1 = __expf(sacc[f][1] + bv[f].y + mmCur[f].y - FIXED_MAX);
      float p2 = __expf(sacc[f][2] + bv[f].z + mmCur[f].z - FIXED_MAX);
      float p3 = __expf(sacc[f][3] + bv[f].w + mmCur[f].w - FIXED_MAX);
      l_q += (p0 + p1) + (p2 + p3);
      uint2 w;
      w.x = (unsigned)f2bf(p0) | ((unsigned)f2bf(p1) << 16);
      w.y = (unsigned)f2bf(p2) | ((unsigned)f2bf(p3) << 16);
      int byte = (lr * 128 + (f * 16 + lg * 4) * 2) ^ ((lr & 7) << 4);
      *reinterpret_cast<uint2*>(pbase + byte) = w;
    }
    asm volatile("s_waitcnt lgkmcnt(0)" ::: "memory");
    SB;
    bf16x8 pa0 = *reinterpret_cast<const bf16x8*>(pbase + pb0);
    bf16x8 pa1 = *reinterpret_cast<const bf16x8*>(pbase + pb1);

    // PV from Vs
    const unsigned short* Vtile = &Vs[i & 1][0];
    __builtin_amdgcn_s_setprio(1);
#pragma unroll
    for (int fd = 0; fd < 4; ++fd) {
      bf16x8 v0 = *reinterpret_cast<const bf16x8*>(Vtile + fd * 1024 + fe0);
      bf16x8 v1 = *reinterpret_cast<const bf16x8*>(Vtile + fd * 1024 + fe1);
      o[fd] = mfma16(pa0, v0, o[fd]);
      o[fd] = mfma16(pa1, v1, o[fd]);
    }
    __builtin_amdgcn_s_setprio(0);

    // drain K/V+bias stage (8 oldest); leave the 4 mask loads in flight
    SB;
    asm volatile("s_waitcnt vmcnt(4)" ::: "memory");
    __builtin_amdgcn_s_barrier();
    SB;
  };

  float4 mmA[4], mmB[4];
  // prologue: stage tile 0, mask 0
  stage(0);
  SB;
  loadMask(mmA, 0);
  asm volatile("s_waitcnt vmcnt(4)" ::: "memory");
  __builtin_amdgcn_s_barrier();
  SB;

  for (int i = 0; i < 32; i += 2) {
    tile(i, mmA, mmB);
    tile(i + 1, mmB, mmA);
  }

  // reduce l over the 4 lane-groups, normalize, scale, write
  l_q += __shfl_xor(l_q, 16);
  l_q += __shfl_xor(l_q, 32);
  float linv = 1.0f / l_q;
  float li0 = __shfl(linv, lg * 4 + 0);
  float li1 = __shfl(linv, lg * 4 + 1);
  float li2 = __shfl(linv, lg * 4 + 2);
  float li3 = __shfl(linv, lg * 4 + 3);
  const float ca = c_attn[h_];
  float li[4] = {li0, li1, li2, li3};
#pragma unroll
  for (int fd = 0; fd < 4; ++fd) {
#pragma unroll
    for (int r = 0; r < 4; ++r) {
      int q_ = q0 + lg * 4 + r;
      int d_ = fd * 16 + lr;
      AO[((size_t)(b_ * 2048 + q_)) * 1024 + h_ * 64 + d_] = f2bf(o[fd][r] * li[r] * ca);
    }
  }
}

extern "C" void kernel_launch(void* const* d_in, const int* in_sizes, int n_in,
                              void* d_out, int out_size, void* d_ws, size_t ws_size,
                              hipStream_t stream) {
  const float* hs   = (const float*)d_in[0];
  const float* bias = (const float*)d_in[1];
  const float* mask = (const float*)d_in[2];
  const float* Wq   = (const float*)d_in[3];
  const float* bq   = (const float*)d_in[4];
  const float* Wk   = (const float*)d_in[5];
  const float* bk   = (const float*)d_in[6];
  const float* Wv   = (const float*)d_in[7];
  const float* bv   = (const float*)d_in[8];
  const float* Wo   = (const float*)d_in[9];
  const float* bo   = (const float*)d_in[10];
  const float* ca   = (const float*)d_in[11];
  float* out = (float*)d_out;

  unsigned short* ws = (unsigned short*)d_ws;
  unsigned short* Xb  = ws;                  // [0, 4194304)
  unsigned short* Wqb = ws + 4194304;        // Wq,Wk,Wv at 1048576 strides
  unsigned short* Wob = Wqb + 3 * 1048576;   // [7340032, 8388608)
  unsigned short* Qb  = ws + 8388608;
  unsigned short* Kb  = Qb + 4194304;
  unsigned short* Vt  = Kb + 4194304;
  unsigned short* AO  = Vt + 4194304;

  cast_all_kernel<<<8192, 256, 0, stream>>>(hs, Wq, Wk, Wv, Wo, ws);

  gemm_qkv<<<dim3(32, 24), 256, 0, stream>>>(Xb, Wqb, bq, bk, bv, Qb, Kb, Vt);
  attn_kernel<<<1024, 256, 0, stream>>>(Qb, Kb, Vt, bias, mask, ca, AO);
  gemm_out<<<dim3(32, 8), 256, 0, stream>>>(AO, Wob, bo, out);
}